// Round 1
// baseline (281.732 us; speedup 1.0000x reference)
//
#include <hip/hip_runtime.h>
#include <cstdint>

// ---------------------------------------------------------------------------
// minerva_transform: logits = (l2(Xe) @ l2(De)^T)^3 @ rh ; preds = sigmoid
// R4: k_minerva rewritten as 256x256-tile, 8-wave, 4-phase/K-tile pipelined
// schedule (T3+T4 counted vmcnt + T5 setprio), raw s_barrier (no vmcnt(0)
// drain in the main loop).  k_embed / k_prep / k_finalize unchanged from R3.
// ---------------------------------------------------------------------------

typedef __attribute__((ext_vector_type(4))) float  f32x4;
typedef __attribute__((ext_vector_type(8))) __bf16 bf16x8;
typedef __attribute__((ext_vector_type(4))) __bf16 bf16x4;

constexpr int B = 4096, N = 20000, F = 768, E = 512;

#define AS1CAST(p) ((__attribute__((address_space(1))) unsigned int*)(uintptr_t)(p))
#define AS3CAST(p) ((__attribute__((address_space(3))) unsigned int*)(uintptr_t)(p))

__device__ __forceinline__ void gload_lds16(const void* g, void* l) {
  // 16B/lane, LDS dest = wave-uniform base + lane*16 (layout guarantees this)
  __builtin_amdgcn_global_load_lds(AS1CAST(g), AS3CAST(l), 16, 0, 0);
}

// ------------------------- fused prep --------------------------------------

__global__ void k_prep(const float* __restrict__ X, const float* __restrict__ D,
                       const float* __restrict__ G, const float* __restrict__ r,
                       const float* __restrict__ hw, const float* __restrict__ hb,
                       __bf16* __restrict__ Xb, __bf16* __restrict__ Db,
                       __bf16* __restrict__ Gb, float* __restrict__ rh,
                       float* __restrict__ lg, float* __restrict__ norm2) {
  const int t = blockIdx.x * blockDim.x + threadIdx.x;
  const int stride = gridDim.x * blockDim.x;
  constexpr int nX = B * F / 4, nD = N * F / 4, nG = E * F / 4;
  constexpr int tot = nX + nD + nG;
  for (int i = t; i < tot; i += stride) {
    const float4* src; bf16x4* dst; int off;
    if (i < nX)           { src = (const float4*)X; dst = (bf16x4*)Xb; off = i; }
    else if (i < nX + nD) { src = (const float4*)D; dst = (bf16x4*)Db; off = i - nX; }
    else                  { src = (const float4*)G; dst = (bf16x4*)Gb; off = i - nX - nD; }
    float4 v = src[off];
    bf16x4 o;
    o[0] = (__bf16)v.x; o[1] = (__bf16)v.y; o[2] = (__bf16)v.z; o[3] = (__bf16)v.w;
    dst[off] = o;
  }
  if (t < N) rh[t] = (2.0f * r[t] - 1.0f) * hw[0] + hb[0];
  if (t < B) lg[t] = 0.0f;
  if (t < B + N) norm2[t] = 0.0f;
}

// ------------------------- combined embedding GEMM -------------------------
// row-tiles 0..31 = X, 32..188 = D.  Eb[g,e] = bf16(sum_k A[m,k]G[e,k]+b[e]),
// norm2[g] += sum_e Eb[g,e]^2.  BK=64, XOR-swizzled LDS (conflict-free).

__global__ __launch_bounds__(256, 3)
void k_embed(const __bf16* __restrict__ Xb, const __bf16* __restrict__ Db,
             const __bf16* __restrict__ Gb, const float* __restrict__ bias,
             __bf16* __restrict__ Eb, float* __restrict__ norm2) {
  constexpr int K = F;  // 768
  __shared__ __bf16 As[128 * 64];
  __shared__ __bf16 Bs[128 * 64];
  __shared__ float ssum[128];
  const int tid  = threadIdx.x;
  const int wave = tid >> 6;
  const int lane = tid & 63;
  const int by = blockIdx.y;
  const bool isX = (by < B / 128);
  const __bf16* A = isX ? Xb : Db;
  const int m0 = isX ? by * 128 : (by - B / 128) * 128;
  const int Mr = isX ? B : N;
  const int g0 = by * 128;              // row offset into Eb / norm2
  const int n0 = blockIdx.x * 128;      // e-dim tile
  if (tid < 128) ssum[tid] = 0.0f;

  // staging: thread t -> row=(t>>3)+q*32, global colgrp (t&7)^(row&7)
  const int srow = tid >> 3;
  const int scg  = (tid & 7) ^ (srow & 7);
  const __bf16* ga[4];
  const __bf16* gb[4];
  __bf16* la[4];
  __bf16* lb[4];
#pragma unroll
  for (int q = 0; q < 4; ++q) {
    const int row = srow + q * 32;
    int arow = m0 + row; if (arow >= Mr) arow = Mr - 1;
    const int brow = n0 + row;                       // < 512 always
    ga[q] = A  + (size_t)arow * K + scg * 8;
    gb[q] = Gb + (size_t)brow * K + scg * 8;
    la[q] = &As[q * 2048 + tid * 8];
    lb[q] = &Bs[q * 2048 + tid * 8];
  }

  const int mw = (wave & 1) * 64;
  const int nw = (wave >> 1) * 64;
  const int quad = lane >> 4;
  const int l15  = lane & 15;
  f32x4 acc[4][4] = {};

  for (int kb = 0; kb < K; kb += 64) {
#pragma unroll
    for (int q = 0; q < 4; ++q) gload_lds16(ga[q] + kb, la[q]);
#pragma unroll
    for (int q = 0; q < 4; ++q) gload_lds16(gb[q] + kb, lb[q]);
    __syncthreads();
#pragma unroll
    for (int h = 0; h < 2; ++h) {
      bf16x8 af[4], bfr[4];
#pragma unroll
      for (int i = 0; i < 4; ++i) {
        const int rr = mw + i * 16 + l15;
        af[i] = *(const bf16x8*)&As[rr * 64 + ((quad + h * 4) ^ (rr & 7)) * 8];
      }
#pragma unroll
      for (int j = 0; j < 4; ++j) {
        const int rr = nw + j * 16 + l15;
        bfr[j] = *(const bf16x8*)&Bs[rr * 64 + ((quad + h * 4) ^ (rr & 7)) * 8];
      }
#pragma unroll
      for (int i = 0; i < 4; ++i)
#pragma unroll
        for (int j = 0; j < 4; ++j)
          acc[i][j] = __builtin_amdgcn_mfma_f32_16x16x32_bf16(af[i], bfr[j], acc[i][j], 0, 0, 0);
    }
    __syncthreads();
  }

  // epilogue: bf16 store + row sum-of-squares.  C/D: col=l15, row=quad*4+reg
#pragma unroll
  for (int i = 0; i < 4; ++i) {
    float part[4] = {0.0f, 0.0f, 0.0f, 0.0f};
#pragma unroll
    for (int j = 0; j < 4; ++j) {
      const int col = n0 + nw + j * 16 + l15;
      const float bv = bias[col];
#pragma unroll
      for (int rr = 0; rr < 4; ++rr) {
        const int row = mw + i * 16 + quad * 4 + rr;   // tile-local
        if (m0 + row < Mr) {
          const __bf16 hv = (__bf16)(acc[i][j][rr] + bv);
          Eb[(size_t)(g0 + row) * E + col] = hv;
          const float vb = (float)hv;
          part[rr] += vb * vb;
        }
      }
    }
#pragma unroll
    for (int rr = 0; rr < 4; ++rr) {
      float v = part[rr];
      v += __shfl_xor(v, 1);
      v += __shfl_xor(v, 2);
      v += __shfl_xor(v, 4);
      v += __shfl_xor(v, 8);
      if (l15 == 0) atomicAdd(&ssum[mw + i * 16 + quad * 4 + rr], v);
    }
  }
  __syncthreads();
  if (tid < 128 && m0 + tid < Mr) atomicAdd(&norm2[g0 + tid], ssum[tid]);
}

// ------------------------- fused Minerva GEMM (256^2, 4-phase pipeline) ----
// acc = Xe@De^T (unnormalized, K=512); epilogue: s^3*rh = acc^3*ix^3*(id^3 rh).
//
// Schedule (per K-tile t, buf = t&1, 4 phases, 2 raw s_barrier each):
//   PH1: ds_read a_lo(8) + b_lo(4); stage (t+1).Blo -> Bs[buf^1][0]; MFMA m0-3 x n0-1
//   PH2: ds_read a_hi(8);           stage (t+1).Bhi -> Bs[buf^1][1]; MFMA m4-7 x n0-1
//   PH3: ds_read b_hi(4);           stage (t+2).Alo -> As[buf  ][0]; MFMA m0-3 x n2-3
//   PH4:                            stage (t+2).Ahi -> As[buf  ][1]; MFMA m4-7 x n2-3
//        s_waitcnt vmcnt(4)   <- ONLY wait in loop: leaves (t+2).A halves in flight
// Overwrite safety: A halves are fully register-resident after PH2's barrier
// (stage at PH3/PH4 targets them); B halves of t+1 land in the idle buffer.
// vmcnt(4) at the tile boundary => newest 4 loads = (t+2).Alo/Ahi, so all of
// tile t+1 (A staged during t-1, B staged during t) is resident.

__global__ __launch_bounds__(512, 2)
void k_minerva(const __bf16* __restrict__ Xe, const __bf16* __restrict__ De,
               const float* __restrict__ norm2, const float* __restrict__ rh,
               float* __restrict__ logits) {
  constexpr int K   = 512;
  constexpr int NKT = K / 64;            // 8 K-tiles
  constexpr int MT  = B / 256;           // 16
  constexpr int NT  = (N + 255) / 256;   // 79
  __shared__ __bf16 As[2][2][128 * 64];  // [buf][half][r*64 + swz-col]
  __shared__ __bf16 Bs[2][2][128 * 64];
  __shared__ float lsum[256];

  const int tid   = threadIdx.x;
  const int wave  = tid >> 6;
  const int lane  = tid & 63;
  const int quad  = lane >> 4;
  const int l15   = lane & 15;
  const int mwave = (wave >> 2) * 128;   // 2 wave-rows
  const int nwave = (wave & 3) * 64;     // 4 wave-cols
  const int ahalf = mwave >> 7;          // which A half this wave reads
  const int bhalf = nwave >> 7;          // which B half this wave reads
  const int brow0 = nwave & 64;          // local row base inside B half

  // XCD-bijective swizzle (1264 % 8 == 0), m-fast within each XCD chunk
  const int wg = (blockIdx.x & 7) * (MT * NT / 8) + (blockIdx.x >> 3);
  const int m0 = (wg & (MT - 1)) * 256;
  const int n0 = (wg >> 4) * 256;

  if (tid < 256) lsum[tid] = 0.0f;

  // ---- staging address precompute -----------------------------------------
  // unit u = q*512 + tid (16B units of one 128x64 half-tile); r = u>>3,
  // stored col-group c_l = u&7 holds global col-group c_l ^ (r&7)  (st_8x XOR)
  const char* XeB = (const char*)Xe;
  const char* DeB = (const char*)De;
  unsigned offA[2][2], offB[2][2];
#pragma unroll
  for (int q = 0; q < 2; ++q) {
    const int u  = q * 512 + tid;
    const int r  = u >> 3;
    const int cg = (u & 7) ^ (r & 7);
#pragma unroll
    for (int hf = 0; hf < 2; ++hf) {
      offA[hf][q] = (unsigned)(m0 + hf * 128 + r) * (K * 2) + cg * 16;
      int br = n0 + hf * 128 + r; if (br >= N) br = N - 1;
      offB[hf][q] = (unsigned)br * (K * 2) + cg * 16;
    }
  }
  const int ldsu = wave * 64 * 8;  // this wave's element offset in a half-tile

#define STAGE_A(kt, hf) do {                                              \
    const int ktc_ = (((kt) < NKT) ? (kt) : (NKT - 1)) * 128;             \
    __bf16* d_ = &As[(kt) & 1][hf][0];                                    \
    gload_lds16(XeB + offA[hf][0] + ktc_, d_ + ldsu);                     \
    gload_lds16(XeB + offA[hf][1] + ktc_, d_ + 4096 + ldsu);              \
  } while (0)
#define STAGE_B(kt, hf) do {                                              \
    const int ktc_ = (((kt) < NKT) ? (kt) : (NKT - 1)) * 128;             \
    __bf16* d_ = &Bs[(kt) & 1][hf][0];                                    \
    gload_lds16(DeB + offB[hf][0] + ktc_, d_ + ldsu);                     \
    gload_lds16(DeB + offB[hf][1] + ktc_, d_ + 4096 + ldsu);              \
  } while (0)

  // ---- prologue: tile0 fully + tile1 A halves (12 loads), keep 4 in flight
  STAGE_A(0, 0); STAGE_A(0, 1); STAGE_B(0, 0); STAGE_B(0, 1);
  STAGE_A(1, 0); STAGE_A(1, 1);
  asm volatile("s_waitcnt vmcnt(4)" ::: "memory");
  __builtin_amdgcn_s_barrier();

  f32x4 acc[8][4] = {};

  for (int t = 0; t < NKT; ++t) {
    const __bf16* Ab = &As[t & 1][ahalf][0];
    const __bf16* Bb = &Bs[t & 1][bhalf][0];
    bf16x8 a_lo[4][2], a_hi[4][2], b_lo[2][2], b_hi[2][2];

    // -------- PH1 --------
#pragma unroll
    for (int i = 0; i < 4; ++i) {
      const int rr = i * 16 + l15;
#pragma unroll
      for (int h = 0; h < 2; ++h)
        a_lo[i][h] = *(const bf16x8*)&Ab[rr * 64 + (((quad + h * 4) ^ (rr & 7)) * 8)];
    }
#pragma unroll
    for (int j = 0; j < 2; ++j) {
      const int rr = brow0 + j * 16 + l15;
#pragma unroll
      for (int h = 0; h < 2; ++h)
        b_lo[j][h] = *(const bf16x8*)&Bb[rr * 64 + (((quad + h * 4) ^ (rr & 7)) * 8)];
    }
    STAGE_B(t + 1, 0);
    __builtin_amdgcn_s_barrier();
    __builtin_amdgcn_s_setprio(1);
#pragma unroll
    for (int h = 0; h < 2; ++h)
#pragma unroll
      for (int i = 0; i < 4; ++i)
#pragma unroll
        for (int j = 0; j < 2; ++j)
          acc[i][j] = __builtin_amdgcn_mfma_f32_16x16x32_bf16(a_lo[i][h], b_lo[j][h], acc[i][j], 0, 0, 0);
    __builtin_amdgcn_s_setprio(0);
    __builtin_amdgcn_s_barrier();

    // -------- PH2 --------
#pragma unroll
    for (int i = 0; i < 4; ++i) {
      const int rr = (i + 4) * 16 + l15;
#pragma unroll
      for (int h = 0; h < 2; ++h)
        a_hi[i][h] = *(const bf16x8*)&Ab[rr * 64 + (((quad + h * 4) ^ (rr & 7)) * 8)];
    }
    STAGE_B(t + 1, 1);
    __builtin_amdgcn_s_barrier();
    __builtin_amdgcn_s_setprio(1);
#pragma unroll
    for (int h = 0; h < 2; ++h)
#pragma unroll
      for (int i = 0; i < 4; ++i)
#pragma unroll
        for (int j = 0; j < 2; ++j)
          acc[i + 4][j] = __builtin_amdgcn_mfma_f32_16x16x32_bf16(a_hi[i][h], b_lo[j][h], acc[i + 4][j], 0, 0, 0);
    __builtin_amdgcn_s_setprio(0);
    __builtin_amdgcn_s_barrier();

    // -------- PH3 --------
#pragma unroll
    for (int j = 0; j < 2; ++j) {
      const int rr = brow0 + (j + 2) * 16 + l15;
#pragma unroll
      for (int h = 0; h < 2; ++h)
        b_hi[j][h] = *(const bf16x8*)&Bb[rr * 64 + (((quad + h * 4) ^ (rr & 7)) * 8)];
    }
    STAGE_A(t + 2, 0);
    __builtin_amdgcn_s_barrier();
    __builtin_amdgcn_s_setprio(1);
#pragma unroll
    for (int h = 0; h < 2; ++h)
#pragma unroll
      for (int i = 0; i < 4; ++i)
#pragma unroll
        for (int j = 0; j < 2; ++j)
          acc[i][j + 2] = __builtin_amdgcn_mfma_f32_16x16x32_bf16(a_lo[i][h], b_hi[j][h], acc[i][j + 2], 0, 0, 0);
    __builtin_amdgcn_s_setprio(0);
    __builtin_amdgcn_s_barrier();

    // -------- PH4 --------
    STAGE_A(t + 2, 1);
    __builtin_amdgcn_s_barrier();
    __builtin_amdgcn_s_setprio(1);
#pragma unroll
    for (int h = 0; h < 2; ++h)
#pragma unroll
      for (int i = 0; i < 4; ++i)
#pragma unroll
        for (int j = 0; j < 2; ++j)
          acc[i + 4][j + 2] = __builtin_amdgcn_mfma_f32_16x16x32_bf16(a_hi[i][h], b_hi[j][h], acc[i + 4][j + 2], 0, 0, 0);
    __builtin_amdgcn_s_setprio(0);
    asm volatile("s_waitcnt vmcnt(4)" ::: "memory");   // counted: (t+2).A in flight
    __builtin_amdgcn_s_barrier();
  }

  asm volatile("s_waitcnt vmcnt(0)" ::: "memory");     // drain trailing stages
  __builtin_amdgcn_s_barrier();

  // ---- epilogue: s^3 weighting folded in; rows = mwave+i*16+quad*4+rr ----
  float id3rh[4];
#pragma unroll
  for (int j = 0; j < 4; ++j) {
    const int col = n0 + nwave + j * 16 + l15;
    if (col < N) {
      const float id = 1.0f / fmaxf(sqrtf(norm2[B + col]), 1e-12f);
      id3rh[j] = id * id * id * rh[col];
    } else id3rh[j] = 0.0f;   // kills padded/clamped cols
  }
#pragma unroll
  for (int i = 0; i < 8; ++i) {
    float ix3[4];
#pragma unroll
    for (int rr = 0; rr < 4; ++rr) {
      const int row = m0 + mwave + i * 16 + quad * 4 + rr;   // < 4096
      const float ix = 1.0f / fmaxf(sqrtf(norm2[row]), 1e-12f);
      ix3[rr] = ix * ix * ix;
    }
    float part[4] = {0.0f, 0.0f, 0.0f, 0.0f};
#pragma unroll
    for (int j = 0; j < 4; ++j)
#pragma unroll
      for (int rr = 0; rr < 4; ++rr) {
        const float a  = acc[i][j][rr];
        const float a2 = a * a;
        part[rr] = fmaf(a2 * a, id3rh[j], part[rr]);
      }
#pragma unroll
    for (int rr = 0; rr < 4; ++rr) {
      float v = part[rr] * ix3[rr];
      v += __shfl_xor(v, 1);
      v += __shfl_xor(v, 2);
      v += __shfl_xor(v, 4);
      v += __shfl_xor(v, 8);
      if (l15 == 0) atomicAdd(&lsum[mwave + i * 16 + quad * 4 + rr], v);
    }
  }
  __syncthreads();
  if (tid < 256) atomicAdd(&logits[m0 + tid], lsum[tid]);
#undef STAGE_A
#undef STAGE_B
}

// ------------------------- finalize ----------------------------------------

__global__ void k_finalize(const float* __restrict__ logits, float* __restrict__ out, int n) {
  int i = blockIdx.x * blockDim.x + threadIdx.x;
  if (i < n) {
    float L = logits[i];
    out[i] = L;
    out[n + i] = 1.0f / (1.0f + expf(-L));
  }
}

// ------------------------- launcher ----------------------------------------

extern "C" void kernel_launch(void* const* d_in, const int* in_sizes, int n_in,
                              void* d_out, int out_size, void* d_ws, size_t ws_size,
                              hipStream_t stream) {
  const float* X   = (const float*)d_in[0];
  const float* D   = (const float*)d_in[1];
  const float* r   = (const float*)d_in[2];
  const float* g_w = (const float*)d_in[3];
  const float* g_b = (const float*)d_in[4];
  const float* h_w = (const float*)d_in[5];
  const float* h_b = (const float*)d_in[6];
  float* out = (float*)d_out;

  // ws layout (bytes), 256-aligned, total ~62.7 MB
  char* ws = (char*)d_ws;
  __bf16* Xb    = (__bf16*)(ws + 0);             // 4096*768*2   = 6,291,456
  __bf16* Db    = (__bf16*)(ws + 6291456);       // 20000*768*2  = 30,720,000
  __bf16* Gb    = (__bf16*)(ws + 37011456);      // 512*768*2    = 786,432
  __bf16* Eb    = (__bf16*)(ws + 37797888);      // 24096*512*2  = 24,674,304
  float*  rh    = (float*) (ws + 62472192);      // 20000*4      = 80,000
  float*  norm2 = (float*) (ws + 62552192);      // 24096*4      = 96,384
  float*  lg    = (float*) (ws + 62648576);      // 4096*4       = 16,384

  // 1. fused convert + rh + zero
  k_prep<<<2048, 256, 0, stream>>>(X, D, g_w, r, h_w, h_b, Xb, Db, Gb, rh, lg, norm2);

  // 2. combined embedding GEMM, bf16 out + norm2 atomics
  k_embed<<<dim3(E / 128, B / 128 + (N + 127) / 128), 256, 0, stream>>>(
      Xb, Db, Gb, g_b, Eb, norm2);

  // 3. fused cosine^3-weighted retrieval, 256^2 tile 4-phase pipeline
  //    grid = 16 m-tiles * 79 n-tiles = 1264 (divisible by 8 XCDs)
  k_minerva<<<16 * 79, 512, 0, stream>>>(Eb, Eb + (size_t)B * E, norm2, rh, lg);

  // 4. logits + sigmoid
  k_finalize<<<(B + 255) / 256, 256, 0, stream>>>(lg, out, B);
}

// Round 2
// 266.517 us; speedup vs baseline: 1.0571x; 1.0571x over previous
//
#include <hip/hip_runtime.h>
#include <cstdint>

// ---------------------------------------------------------------------------
// minerva_transform: logits = (l2(Xe) @ l2(De)^T)^3 @ rh ; preds = sigmoid
// R5: same 256x256 4-phase pipelined k_minerva as R4, but spill-fix:
//   - #pragma unroll 1 on the K-loop (R4 fully unrolled -> LICM hoisted
//     per-phase LDS addresses across 8 iterations -> arch-VGPR cap 128 hit ->
//     scratch spills in the main loop; evidence: WRITE_SIZE 2.5->19 MB).
//   - staging offsets slimmed (offA[2][2] -> offA0[2] + folded constant).
// k_embed / k_prep / k_finalize unchanged.
// ---------------------------------------------------------------------------

typedef __attribute__((ext_vector_type(4))) float  f32x4;
typedef __attribute__((ext_vector_type(8))) __bf16 bf16x8;
typedef __attribute__((ext_vector_type(4))) __bf16 bf16x4;

constexpr int B = 4096, N = 20000, F = 768, E = 512;

#define AS1CAST(p) ((__attribute__((address_space(1))) unsigned int*)(uintptr_t)(p))
#define AS3CAST(p) ((__attribute__((address_space(3))) unsigned int*)(uintptr_t)(p))

__device__ __forceinline__ void gload_lds16(const void* g, void* l) {
  // 16B/lane, LDS dest = wave-uniform base + lane*16 (layout guarantees this)
  __builtin_amdgcn_global_load_lds(AS1CAST(g), AS3CAST(l), 16, 0, 0);
}

// ------------------------- fused prep --------------------------------------

__global__ void k_prep(const float* __restrict__ X, const float* __restrict__ D,
                       const float* __restrict__ G, const float* __restrict__ r,
                       const float* __restrict__ hw, const float* __restrict__ hb,
                       __bf16* __restrict__ Xb, __bf16* __restrict__ Db,
                       __bf16* __restrict__ Gb, float* __restrict__ rh,
                       float* __restrict__ lg, float* __restrict__ norm2) {
  const int t = blockIdx.x * blockDim.x + threadIdx.x;
  const int stride = gridDim.x * blockDim.x;
  constexpr int nX = B * F / 4, nD = N * F / 4, nG = E * F / 4;
  constexpr int tot = nX + nD + nG;
  for (int i = t; i < tot; i += stride) {
    const float4* src; bf16x4* dst; int off;
    if (i < nX)           { src = (const float4*)X; dst = (bf16x4*)Xb; off = i; }
    else if (i < nX + nD) { src = (const float4*)D; dst = (bf16x4*)Db; off = i - nX; }
    else                  { src = (const float4*)G; dst = (bf16x4*)Gb; off = i - nX - nD; }
    float4 v = src[off];
    bf16x4 o;
    o[0] = (__bf16)v.x; o[1] = (__bf16)v.y; o[2] = (__bf16)v.z; o[3] = (__bf16)v.w;
    dst[off] = o;
  }
  if (t < N) rh[t] = (2.0f * r[t] - 1.0f) * hw[0] + hb[0];
  if (t < B) lg[t] = 0.0f;
  if (t < B + N) norm2[t] = 0.0f;
}

// ------------------------- combined embedding GEMM -------------------------
// row-tiles 0..31 = X, 32..188 = D.  Eb[g,e] = bf16(sum_k A[m,k]G[e,k]+b[e]),
// norm2[g] += sum_e Eb[g,e]^2.  BK=64, XOR-swizzled LDS (conflict-free).

__global__ __launch_bounds__(256, 3)
void k_embed(const __bf16* __restrict__ Xb, const __bf16* __restrict__ Db,
             const __bf16* __restrict__ Gb, const float* __restrict__ bias,
             __bf16* __restrict__ Eb, float* __restrict__ norm2) {
  constexpr int K = F;  // 768
  __shared__ __bf16 As[128 * 64];
  __shared__ __bf16 Bs[128 * 64];
  __shared__ float ssum[128];
  const int tid  = threadIdx.x;
  const int wave = tid >> 6;
  const int lane = tid & 63;
  const int by = blockIdx.y;
  const bool isX = (by < B / 128);
  const __bf16* A = isX ? Xb : Db;
  const int m0 = isX ? by * 128 : (by - B / 128) * 128;
  const int Mr = isX ? B : N;
  const int g0 = by * 128;              // row offset into Eb / norm2
  const int n0 = blockIdx.x * 128;      // e-dim tile
  if (tid < 128) ssum[tid] = 0.0f;

  // staging: thread t -> row=(t>>3)+q*32, global colgrp (t&7)^(row&7)
  const int srow = tid >> 3;
  const int scg  = (tid & 7) ^ (srow & 7);
  const __bf16* ga[4];
  const __bf16* gb[4];
  __bf16* la[4];
  __bf16* lb[4];
#pragma unroll
  for (int q = 0; q < 4; ++q) {
    const int row = srow + q * 32;
    int arow = m0 + row; if (arow >= Mr) arow = Mr - 1;
    const int brow = n0 + row;                       // < 512 always
    ga[q] = A  + (size_t)arow * K + scg * 8;
    gb[q] = Gb + (size_t)brow * K + scg * 8;
    la[q] = &As[q * 2048 + tid * 8];
    lb[q] = &Bs[q * 2048 + tid * 8];
  }

  const int mw = (wave & 1) * 64;
  const int nw = (wave >> 1) * 64;
  const int quad = lane >> 4;
  const int l15  = lane & 15;
  f32x4 acc[4][4] = {};

  for (int kb = 0; kb < K; kb += 64) {
#pragma unroll
    for (int q = 0; q < 4; ++q) gload_lds16(ga[q] + kb, la[q]);
#pragma unroll
    for (int q = 0; q < 4; ++q) gload_lds16(gb[q] + kb, lb[q]);
    __syncthreads();
#pragma unroll
    for (int h = 0; h < 2; ++h) {
      bf16x8 af[4], bfr[4];
#pragma unroll
      for (int i = 0; i < 4; ++i) {
        const int rr = mw + i * 16 + l15;
        af[i] = *(const bf16x8*)&As[rr * 64 + ((quad + h * 4) ^ (rr & 7)) * 8];
      }
#pragma unroll
      for (int j = 0; j < 4; ++j) {
        const int rr = nw + j * 16 + l15;
        bfr[j] = *(const bf16x8*)&Bs[rr * 64 + ((quad + h * 4) ^ (rr & 7)) * 8];
      }
#pragma unroll
      for (int i = 0; i < 4; ++i)
#pragma unroll
        for (int j = 0; j < 4; ++j)
          acc[i][j] = __builtin_amdgcn_mfma_f32_16x16x32_bf16(af[i], bfr[j], acc[i][j], 0, 0, 0);
    }
    __syncthreads();
  }

  // epilogue: bf16 store + row sum-of-squares.  C/D: col=l15, row=quad*4+reg
#pragma unroll
  for (int i = 0; i < 4; ++i) {
    float part[4] = {0.0f, 0.0f, 0.0f, 0.0f};
#pragma unroll
    for (int j = 0; j < 4; ++j) {
      const int col = n0 + nw + j * 16 + l15;
      const float bv = bias[col];
#pragma unroll
      for (int rr = 0; rr < 4; ++rr) {
        const int row = mw + i * 16 + quad * 4 + rr;   // tile-local
        if (m0 + row < Mr) {
          const __bf16 hv = (__bf16)(acc[i][j][rr] + bv);
          Eb[(size_t)(g0 + row) * E + col] = hv;
          const float vb = (float)hv;
          part[rr] += vb * vb;
        }
      }
    }
#pragma unroll
    for (int rr = 0; rr < 4; ++rr) {
      float v = part[rr];
      v += __shfl_xor(v, 1);
      v += __shfl_xor(v, 2);
      v += __shfl_xor(v, 4);
      v += __shfl_xor(v, 8);
      if (l15 == 0) atomicAdd(&ssum[mw + i * 16 + quad * 4 + rr], v);
    }
  }
  __syncthreads();
  if (tid < 128 && m0 + tid < Mr) atomicAdd(&norm2[g0 + tid], ssum[tid]);
}

// ------------------------- fused Minerva GEMM (256^2, 4-phase pipeline) ----
// acc = Xe@De^T (unnormalized, K=512); epilogue: s^3*rh = acc^3*ix^3*(id^3 rh).
//
// Schedule per K-tile t (buf = t&1), phases = {ds_read; stage-issue; barrier;
// setprio(1); 16 MFMA; setprio(0); barrier}:
//   PH1: read a_lo(8)+b_lo(4); stage (t+1).Blo -> Bs[buf^1][0]; MFMA m0-3 x n0-1
//   PH2: read a_hi(8);         stage (t+1).Bhi -> Bs[buf^1][1]; MFMA m4-7 x n0-1
//   PH3: read b_hi(4);         stage (t+2).Alo -> As[buf  ][0]; MFMA m0-3 x n2-3
//   PH4:                       stage (t+2).Ahi -> As[buf  ][1]; MFMA m4-7 x n2-3
//        s_waitcnt vmcnt(4)  <- ONLY wait in loop; (t+2).A stays in flight.
// A-half LDS reads finish at PH2 -> PH3/PH4 may overwrite As[buf]; B stages
// always target the idle buffer.  vmcnt(4) at tile end => A(t+1),B(t+1) are
// resident for the next iteration.
// #pragma unroll 1: prevents full-unroll LICM from hoisting 8 iterations of
// LDS addresses (R4's spill cause).

__global__ __launch_bounds__(512, 2)
void k_minerva(const __bf16* __restrict__ Xe, const __bf16* __restrict__ De,
               const float* __restrict__ norm2, const float* __restrict__ rh,
               float* __restrict__ logits) {
  constexpr int K   = 512;
  constexpr int NKT = K / 64;            // 8 K-tiles
  constexpr int MT  = B / 256;           // 16
  constexpr int NT  = (N + 255) / 256;   // 79
  __shared__ __bf16 As[2][2][128 * 64];  // [buf][half][r*64 + swz-col]
  __shared__ __bf16 Bs[2][2][128 * 64];
  __shared__ float lsum[256];

  const int tid   = threadIdx.x;
  const int wave  = tid >> 6;
  const int lane  = tid & 63;
  const int quad  = lane >> 4;
  const int l15   = lane & 15;
  const int mwave = (wave >> 2) * 128;   // 2 wave-rows
  const int nwave = (wave & 3) * 64;     // 4 wave-cols
  const int ahalf = mwave >> 7;          // which A half this wave reads
  const int bhalf = nwave >> 7;          // which B half this wave reads
  const int brow0 = nwave & 64;          // local row base inside B half

  // XCD-bijective swizzle (1264 % 8 == 0), m-fast within each XCD chunk
  const int wg = (blockIdx.x & 7) * (MT * NT / 8) + (blockIdx.x >> 3);
  const int m0 = (wg & (MT - 1)) * 256;
  const int n0 = (wg >> 4) * 256;

  if (tid < 256) lsum[tid] = 0.0f;

  // ---- staging address precompute -----------------------------------------
  // unit u = q*512 + tid (16B units of one 128x64 half-tile); r = u>>3,
  // stored col-group c_l = u&7 holds global col-group c_l ^ (r&7)  (st_8x XOR)
  const char* XeB = (const char*)Xe;
  const char* DeB = (const char*)De;
  unsigned offA0[2], offB[2][2];
#pragma unroll
  for (int q = 0; q < 2; ++q) {
    const int u  = q * 512 + tid;
    const int r  = u >> 3;
    const int cg = (u & 7) ^ (r & 7);
    offA0[q] = (unsigned)(m0 + r) * (K * 2) + cg * 16;
#pragma unroll
    for (int hf = 0; hf < 2; ++hf) {
      int br = n0 + hf * 128 + r; if (br >= N) br = N - 1;
      offB[hf][q] = (unsigned)br * (K * 2) + cg * 16;
    }
  }
  const int ldsu = wave * 512;  // this wave's element offset in a half-tile

#define STAGE_A(kt, hf) do {                                              \
    const int ktc_ = (((kt) < NKT) ? (kt) : (NKT - 1)) * 128;             \
    __bf16* d_ = &As[(kt) & 1][hf][0];                                    \
    gload_lds16(XeB + offA0[0] + (hf) * (128 * K * 2) + ktc_, d_ + ldsu); \
    gload_lds16(XeB + offA0[1] + (hf) * (128 * K * 2) + ktc_, d_ + 4096 + ldsu); \
  } while (0)
#define STAGE_B(kt, hf) do {                                              \
    const int ktc_ = (((kt) < NKT) ? (kt) : (NKT - 1)) * 128;             \
    __bf16* d_ = &Bs[(kt) & 1][hf][0];                                    \
    gload_lds16(DeB + offB[hf][0] + ktc_, d_ + ldsu);                     \
    gload_lds16(DeB + offB[hf][1] + ktc_, d_ + 4096 + ldsu);              \
  } while (0)

  // ---- prologue: tile0 fully + tile1 A halves (12 loads), keep 4 in flight
  STAGE_A(0, 0); STAGE_A(0, 1); STAGE_B(0, 0); STAGE_B(0, 1);
  STAGE_A(1, 0); STAGE_A(1, 1);
  asm volatile("s_waitcnt vmcnt(4)" ::: "memory");
  __builtin_amdgcn_s_barrier();

  f32x4 acc[8][4] = {};

#pragma unroll 1
  for (int t = 0; t < NKT; ++t) {
    const __bf16* Ab = &As[t & 1][ahalf][0];
    const __bf16* Bb = &Bs[t & 1][bhalf][0];
    bf16x8 a_lo[4][2], a_hi[4][2], b_lo[2][2], b_hi[2][2];

    // -------- PH1 --------
#pragma unroll
    for (int i = 0; i < 4; ++i) {
      const int rr = i * 16 + l15;
#pragma unroll
      for (int h = 0; h < 2; ++h)
        a_lo[i][h] = *(const bf16x8*)&Ab[rr * 64 + (((quad + h * 4) ^ (rr & 7)) * 8)];
    }
#pragma unroll
    for (int j = 0; j < 2; ++j) {
      const int rr = brow0 + j * 16 + l15;
#pragma unroll
      for (int h = 0; h < 2; ++h)
        b_lo[j][h] = *(const bf16x8*)&Bb[rr * 64 + (((quad + h * 4) ^ (rr & 7)) * 8)];
    }
    STAGE_B(t + 1, 0);
    __builtin_amdgcn_s_barrier();
    __builtin_amdgcn_s_setprio(1);
#pragma unroll
    for (int h = 0; h < 2; ++h)
#pragma unroll
      for (int i = 0; i < 4; ++i)
#pragma unroll
        for (int j = 0; j < 2; ++j)
          acc[i][j] = __builtin_amdgcn_mfma_f32_16x16x32_bf16(a_lo[i][h], b_lo[j][h], acc[i][j], 0, 0, 0);
    __builtin_amdgcn_s_setprio(0);
    __builtin_amdgcn_s_barrier();

    // -------- PH2 --------
#pragma unroll
    for (int i = 0; i < 4; ++i) {
      const int rr = (i + 4) * 16 + l15;
#pragma unroll
      for (int h = 0; h < 2; ++h)
        a_hi[i][h] = *(const bf16x8*)&Ab[rr * 64 + (((quad + h * 4) ^ (rr & 7)) * 8)];
    }
    STAGE_B(t + 1, 1);
    __builtin_amdgcn_s_barrier();
    __builtin_amdgcn_s_setprio(1);
#pragma unroll
    for (int h = 0; h < 2; ++h)
#pragma unroll
      for (int i = 0; i < 4; ++i)
#pragma unroll
        for (int j = 0; j < 2; ++j)
          acc[i + 4][j] = __builtin_amdgcn_mfma_f32_16x16x32_bf16(a_hi[i][h], b_lo[j][h], acc[i + 4][j], 0, 0, 0);
    __builtin_amdgcn_s_setprio(0);
    __builtin_amdgcn_s_barrier();

    // -------- PH3 --------
#pragma unroll
    for (int j = 0; j < 2; ++j) {
      const int rr = brow0 + (j + 2) * 16 + l15;
#pragma unroll
      for (int h = 0; h < 2; ++h)
        b_hi[j][h] = *(const bf16x8*)&Bb[rr * 64 + (((quad + h * 4) ^ (rr & 7)) * 8)];
    }
    STAGE_A(t + 2, 0);
    __builtin_amdgcn_s_barrier();
    __builtin_amdgcn_s_setprio(1);
#pragma unroll
    for (int h = 0; h < 2; ++h)
#pragma unroll
      for (int i = 0; i < 4; ++i)
#pragma unroll
        for (int j = 0; j < 2; ++j)
          acc[i][j + 2] = __builtin_amdgcn_mfma_f32_16x16x32_bf16(a_lo[i][h], b_hi[j][h], acc[i][j + 2], 0, 0, 0);
    __builtin_amdgcn_s_setprio(0);
    __builtin_amdgcn_s_barrier();

    // -------- PH4 --------
    STAGE_A(t + 2, 1);
    __builtin_amdgcn_s_barrier();
    __builtin_amdgcn_s_setprio(1);
#pragma unroll
    for (int h = 0; h < 2; ++h)
#pragma unroll
      for (int i = 0; i < 4; ++i)
#pragma unroll
        for (int j = 0; j < 2; ++j)
          acc[i + 4][j + 2] = __builtin_amdgcn_mfma_f32_16x16x32_bf16(a_hi[i][h], b_hi[j][h], acc[i + 4][j + 2], 0, 0, 0);
    __builtin_amdgcn_s_setprio(0);
    asm volatile("s_waitcnt vmcnt(4)" ::: "memory");   // counted: (t+2).A in flight
    __builtin_amdgcn_s_barrier();
  }

  asm volatile("s_waitcnt vmcnt(0)" ::: "memory");     // drain trailing stages
  __builtin_amdgcn_s_barrier();

  // ---- epilogue: s^3 weighting folded in; rows = mwave+i*16+quad*4+rr ----
  float id3rh[4];
#pragma unroll
  for (int j = 0; j < 4; ++j) {
    const int col = n0 + nwave + j * 16 + l15;
    if (col < N) {
      const float id = 1.0f / fmaxf(sqrtf(norm2[B + col]), 1e-12f);
      id3rh[j] = id * id * id * rh[col];
    } else id3rh[j] = 0.0f;   // kills padded/clamped cols
  }
#pragma unroll
  for (int i = 0; i < 8; ++i) {
    float ix3[4];
#pragma unroll
    for (int rr = 0; rr < 4; ++rr) {
      const int row = m0 + mwave + i * 16 + quad * 4 + rr;   // < 4096
      const float ix = 1.0f / fmaxf(sqrtf(norm2[row]), 1e-12f);
      ix3[rr] = ix * ix * ix;
    }
    float part[4] = {0.0f, 0.0f, 0.0f, 0.0f};
#pragma unroll
    for (int j = 0; j < 4; ++j)
#pragma unroll
      for (int rr = 0; rr < 4; ++rr) {
        const float a  = acc[i][j][rr];
        const float a2 = a * a;
        part[rr] = fmaf(a2 * a, id3rh[j], part[rr]);
      }
#pragma unroll
    for (int rr = 0; rr < 4; ++rr) {
      float v = part[rr] * ix3[rr];
      v += __shfl_xor(v, 1);
      v += __shfl_xor(v, 2);
      v += __shfl_xor(v, 4);
      v += __shfl_xor(v, 8);
      if (l15 == 0) atomicAdd(&lsum[mwave + i * 16 + quad * 4 + rr], v);
    }
  }
  __syncthreads();
  if (tid < 256) atomicAdd(&logits[m0 + tid], lsum[tid]);
#undef STAGE_A
#undef STAGE_B
}

// ------------------------- finalize ----------------------------------------

__global__ void k_finalize(const float* __restrict__ logits, float* __restrict__ out, int n) {
  int i = blockIdx.x * blockDim.x + threadIdx.x;
  if (i < n) {
    float L = logits[i];
    out[i] = L;
    out[n + i] = 1.0f / (1.0f + expf(-L));
  }
}

// ------------------------- launcher ----------------------------------------

extern "C" void kernel_launch(void* const* d_in, const int* in_sizes, int n_in,
                              void* d_out, int out_size, void* d_ws, size_t ws_size,
                              hipStream_t stream) {
  const float* X   = (const float*)d_in[0];
  const float* D   = (const float*)d_in[1];
  const float* r   = (const float*)d_in[2];
  const float* g_w = (const float*)d_in[3];
  const float* g_b = (const float*)d_in[4];
  const float* h_w = (const float*)d_in[5];
  const float* h_b = (const float*)d_in[6];
  float* out = (float*)d_out;

  // ws layout (bytes), 256-aligned, total ~62.7 MB
  char* ws = (char*)d_ws;
  __bf16* Xb    = (__bf16*)(ws + 0);             // 4096*768*2   = 6,291,456
  __bf16* Db    = (__bf16*)(ws + 6291456);       // 20000*768*2  = 30,720,000
  __bf16* Gb    = (__bf16*)(ws + 37011456);      // 512*768*2    = 786,432
  __bf16* Eb    = (__bf16*)(ws + 37797888);      // 24096*512*2  = 24,674,304
  float*  rh    = (float*) (ws + 62472192);      // 20000*4      = 80,000
  float*  norm2 = (float*) (ws + 62552192);      // 24096*4      = 96,384
  float*  lg    = (float*) (ws + 62648576);      // 4096*4       = 16,384

  // 1. fused convert + rh + zero
  k_prep<<<2048, 256, 0, stream>>>(X, D, g_w, r, h_w, h_b, Xb, Db, Gb, rh, lg, norm2);

  // 2. combined embedding GEMM, bf16 out + norm2 atomics
  k_embed<<<dim3(E / 128, B / 128 + (N + 127) / 128), 256, 0, stream>>>(
      Xb, Db, Gb, g_b, Eb, norm2);

  // 3. fused cosine^3-weighted retrieval, 256^2 tile 4-phase pipeline
  //    grid = 16 m-tiles * 79 n-tiles = 1264 (divisible by 8 XCDs)
  k_minerva<<<16 * 79, 512, 0, stream>>>(Eb, Eb + (size_t)B * E, norm2, rh, lg);

  // 4. logits + sigmoid
  k_finalize<<<(B + 255) / 256, 256, 0, stream>>>(lg, out, B);
}